// Round 5
// baseline (166.618 us; speedup 1.0000x reference)
//
#include <hip/hip_runtime.h>

// ---------- helpers ----------
__device__ __forceinline__ unsigned short f2b(float f) {
    unsigned int u = __builtin_bit_cast(unsigned int, f);
    u += 0x7fffu + ((u >> 16) & 1u);   // round-to-nearest-even
    return (unsigned short)(u >> 16);
}
__device__ __forceinline__ float fastrcp(float x) {
    return __builtin_amdgcn_rcpf(x);   // ~1e-7 rel err, invisible under bf16
}
// packed f32x2 -> bf16x2 (RTNE, same rounding as f2b), 1 instruction
__device__ __forceinline__ unsigned int cvt_pk_bf16(float lo, float hi) {
    unsigned int r;
    asm("v_cvt_pk_bf16_f32 %0, %1, %2" : "=v"(r) : "v"(lo), "v"(hi));
    return r;
}
// DPP wave64 sum: after chain, lane 63 holds the full sum; broadcast via readlane.
template<int CTRL>
__device__ __forceinline__ float dpp_add(float x) {
    int s = __builtin_amdgcn_update_dpp(0, __builtin_bit_cast(int, x), CTRL, 0xf, 0xf, true);
    return x + __builtin_bit_cast(float, s);
}
__device__ __forceinline__ float wave_sum_bcast(float x) {
    x = dpp_add<0x111>(x);   // row_shr:1
    x = dpp_add<0x112>(x);   // row_shr:2
    x = dpp_add<0x114>(x);   // row_shr:4
    x = dpp_add<0x118>(x);   // row_shr:8  -> lane 15/31/47/63 = row sums
    x = dpp_add<0x142>(x);   // row_bcast:15
    x = dpp_add<0x143>(x);   // row_bcast:31 -> lane 63 = total
    return __builtin_bit_cast(float,
        __builtin_amdgcn_readlane(__builtin_bit_cast(int, x), 63));
}

typedef short bf16x8_t __attribute__((ext_vector_type(8)));
typedef float f32x4_t  __attribute__((ext_vector_type(4)));

// Problem dims
#define NB   16384   // batch
#define AD   1024    // A dim
#define YD   128     // output dim

// =====================================================================
// Kernel 1: Vt in FRAGMENT-MAJOR layout (unchanged — validated).
//   Logical B row n (0..255), col a (0..1023):  val = Kp[a][n>>7]*U[2a+(n>>7)][n&127]
//   Physical: T=n>>4, rr=n&15, CQ=a>>3, e=a&7
//             Vtf[T*16384 + CQ*128 + rr*8 + e]
// =====================================================================
__global__ __launch_bounds__(256) void vt_kernel(
    const float* __restrict__ Kq,   // [1024][2] f32
    const float* __restrict__ U,    // [2048][128] f32
    unsigned short* __restrict__ Vtf) // [16][128][16][8] bf16
{
    int o  = blockIdx.x * 256 + threadIdx.x;
    int T  = o >> 14;
    int CQ = (o >> 7) & 127;
    int rr = (o >> 3) & 15;
    int e  = o & 7;
    int n  = T * 16 + rr;
    int a  = CQ * 8 + e;
    int j  = n >> 7;
    int y  = n & 127;
    float k  = Kq[2 * a + j];
    float uv = U[(size_t)(2 * a + j) * YD + y];
    Vtf[o] = f2b(k * k * uv);
}

// =====================================================================
// Kernel 2: FUSED row-solve + GEMM + combine.
// 512 threads (8 waves), BM=16 rows/block, 1024 blocks.
// LDS = 32KB A-tile + 128B bf -> 4 blocks/CU = 32 waves/CU = 8 waves/SIMD
// (VGPR forced <=64 via __launch_bounds__(512,8); measured 52 at BM=32).
// Phase 1: wave w owns rows w*2, w*2+1 (both loaded upfront). Moments ->
//          DPP wave-sum -> 8-iter closed-form solve -> af bf16 via
//          v_cvt_pk_bf16_f32 into swizzled LDS A-tile.  (validated math)
// Phase 2: barrier-free k-loop; wave w owns n-tiles {w, w+8} (the
//          (y, y+128) pair); A frags from LDS, B frags reg-dbuf
//          straight from L2 (fragment-major Vtf).
// =====================================================================
__global__ __launch_bounds__(512, 8) void fused_kernel(
    const float* __restrict__ AT,            // [16384][1024] f32
    const float* __restrict__ Kq,            // [1024][2] f32
    const float* __restrict__ BTv,           // [2] f32
    const unsigned short* __restrict__ Vtf,  // fragment-major bf16
    const float* __restrict__ bias,          // [128] f32
    float* __restrict__ out)                 // [16384][128] f32
{
    __shared__ __align__(16) unsigned short lA[16 * 1024];    // 32 KB
    __shared__ float lbf[16][2];

    const int t    = threadIdx.x;
    const int lane = t & 63;
    const int w    = t >> 6;          // wave id 0..7
    const int mtile = blockIdx.x;     // 0..1023

    // =================== Phase 1: row solve (2 rows/wave) ===================
    // lane owns columns a = c*256 + lane*4 + e, c=0..3, e=0..3
    float kp0[16], kp1[16];
#pragma unroll
    for (int c = 0; c < 4; ++c) {
        int base = c * 256 + lane * 4;
        float4 k0v = *(const float4*)(Kq + 2 * base);
        float4 k1v = *(const float4*)(Kq + 2 * base + 4);
        kp0[c * 4 + 0] = k0v.x * k0v.x; kp1[c * 4 + 0] = k0v.y * k0v.y;
        kp0[c * 4 + 1] = k0v.z * k0v.z; kp1[c * 4 + 1] = k0v.w * k0v.w;
        kp0[c * 4 + 2] = k1v.x * k1v.x; kp1[c * 4 + 2] = k1v.y * k1v.y;
        kp0[c * 4 + 3] = k1v.z * k1v.z; kp1[c * 4 + 3] = k1v.w * k1v.w;
    }
    const float bt0 = BTv[0], bt1 = BTv[1];

    const float* atb = AT + (size_t)(mtile * 16 + w * 2) * AD;

    float ta[2][16];   // both rows loaded upfront (8 independent dwordx4)
#pragma unroll
    for (int r = 0; r < 2; ++r) {
#pragma unroll
        for (int c = 0; c < 4; ++c) {
            float4 av = *(const float4*)(atb + (size_t)r * AD + c * 256 + lane * 4);
            ta[r][c * 4 + 0] = av.x; ta[r][c * 4 + 1] = av.y;
            ta[r][c * 4 + 2] = av.z; ta[r][c * 4 + 3] = av.w;
        }
    }

#pragma unroll
    for (int r = 0; r < 2; ++r) {
        // moments: 0:M0 1:M1 2:M00 3:M01 4:M11 5:M000 6:M001 7:M011 8:M111
        float M[9];
#pragma unroll
        for (int i2 = 0; i2 < 9; ++i2) M[i2] = 0.f;
#pragma unroll
        for (int e = 0; e < 16; ++e) {
            float tv = ta[r][e], p = kp0[e], q2 = kp1[e];
            float u0 = tv * p, u1 = tv * q2;
            M[0] += u0; M[1] += u1;
            float u00 = u0 * p, u01 = u0 * q2, u11 = u1 * q2;
            M[2] += u00; M[3] += u01; M[4] += u11;
            M[5] += u00 * p; M[6] += u00 * q2; M[7] += u01 * q2; M[8] += u11 * q2;
        }
        // DPP reduce (no DS ops), result uniform via readlane
#pragma unroll
        for (int i2 = 0; i2 < 9; ++i2) M[i2] = wave_sum_bcast(M[i2]);

        float bf0 = 0.f, bf1 = 0.f;
#pragma unroll
        for (int it = 0; it < 8; ++it) {
            float q00 = bf0 * bf0, q01 = bf0 * bf1, q11 = bf1 * bf1;
            float s0 = M[0] - (bf0 * M[2] + bf1 * M[3]) + (q00 * M[5] + 2.f * q01 * M[6] + q11 * M[7]);
            float s1 = M[1] - (bf0 * M[3] + bf1 * M[4]) + (q00 * M[6] + 2.f * q01 * M[7] + q11 * M[8]);
            bf0 = bt0 * fastrcp(1.f + s0);
            bf1 = bt1 * fastrcp(1.f + s1);
        }
        const int m = w * 2 + r;
        if (lane == 0) { lbf[m][0] = bf0; lbf[m][1] = bf1; }

        // af -> bf16 (cvt_pk, RTNE) -> swizzled LDS A-tile (layout unchanged)
#pragma unroll
        for (int c = 0; c < 4; ++c) {
            float v[4];
#pragma unroll
            for (int e = 0; e < 4; ++e) {
                int idx = c * 4 + e;
                v[e] = ta[r][idx] * fastrcp(1.f + bf0 * kp0[idx] + bf1 * kp1[idx]);
            }
            uint2 pk;
            pk.x = cvt_pk_bf16(v[0], v[1]);
            pk.y = cvt_pk_bf16(v[2], v[3]);
            int cg = c * 4 + (lane >> 4);
            int cl = (lane >> 1) & 7;
            int off = (m * 128 + cg * 8 + (cl ^ (m & 7))) * 8 + (lane & 1) * 4;
            *(uint2*)(&lA[off]) = pk;
        }
    }

    __syncthreads();   // the ONLY barrier: lA/lbf now visible to all waves

    // =================== Phase 2: barrier-free GEMM ===================
    const int rr = lane & 15;      // row/col within 16-tile
    const int hb = lane >> 4;      // quarter-wave
    const int rx = rr & 7;         // A-swizzle key (m-row = rr, (rr&7))

    // wave w owns n-tiles {w, w+8}: y = w*16+rr and y+128
    const unsigned short* pB = Vtf + (size_t)w * 16384 + hb * 128 + rr * 8;

    f32x4_t acc[2];
#pragma unroll
    for (int j = 0; j < 2; ++j) acc[j] = (f32x4_t){0.f, 0.f, 0.f, 0.f};

    bf16x8_t fbA[2], fbB[2];

    auto loadB = [&](bf16x8_t* fb, int k0, int kk) {
        int ke = k0 * 16 + kk * 512;              // uniform elem offset
        fb[0] = *(const bf16x8_t*)(pB + ke);            // tile w
        fb[1] = *(const bf16x8_t*)(pB + ke + 131072);   // tile w+8
    };
    auto compute = [&](const bf16x8_t* fb, int k0, int kk) {
        const int cq = kk * 4 + hb;
        bf16x8_t fa = *(const bf16x8_t*)(
            &lA[((rr * 128) + (k0 >> 6) * 8 + (cq ^ rx)) * 8]);
#pragma unroll
        for (int j = 0; j < 2; ++j)
            acc[j] = __builtin_amdgcn_mfma_f32_16x16x32_bf16(fa, fb[j], acc[j], 0, 0, 0);
    };

    loadB(fbA, 0, 0);
    loadB(fbB, 0, 1);
#pragma unroll 1
    for (int k0 = 0; k0 < AD; k0 += 64) {
        __builtin_amdgcn_s_setprio(1);
        compute(fbA, k0, 0);
        __builtin_amdgcn_s_setprio(0);
        if (k0 + 64 < AD) loadB(fbA, k0 + 64, 0);
        __builtin_amdgcn_s_setprio(1);
        compute(fbB, k0, 1);
        __builtin_amdgcn_s_setprio(0);
        if (k0 + 64 < AD) loadB(fbB, k0 + 64, 1);
    }

    // =================== Epilogue ===================
    // C/D layout: col = lane&15 (n within tile), row = (lane>>4)*4 + reg.
    // acc[0] (tile w, y-cols) pairs with acc[1] (tile w+8, y+128 cols).
    const int mloc  = hb * 4;
    const int mbase = mtile * 16 + mloc;
    float2 bfv[4];
#pragma unroll
    for (int r = 0; r < 4; ++r)
        bfv[r] = *(const float2*)(&lbf[mloc + r][0]);
    const int y = w * 16 + rr;
    const float bv = bias[y];
#pragma unroll
    for (int r = 0; r < 4; ++r) {
        float val = bfv[r].x * acc[0][r] + bfv[r].y * acc[1][r] + bv;
        out[(size_t)(mbase + r) * YD + y] = val;
    }
}

// =====================================================================
extern "C" void kernel_launch(void* const* d_in, const int* in_sizes, int n_in,
                              void* d_out, int out_size, void* d_ws, size_t ws_size,
                              hipStream_t stream) {
    const float* AT  = (const float*)d_in[0];  // [16384][1024] f32
    const float* Kq  = (const float*)d_in[1];  // [1024][2] f32
    const float* BTv = (const float*)d_in[2];  // [2] f32
    const float* U   = (const float*)d_in[3];  // [2048][128] f32
    const float* bia = (const float*)d_in[4];  // [128] f32
    float* out = (float*)d_out;

    unsigned short* Vtf = (unsigned short*)d_ws;  // 512 KB bf16 fragment-major

    vt_kernel<<<dim3(1024), dim3(256), 0, stream>>>(Kq, U, Vtf);
    fused_kernel<<<dim3(NB / 16), dim3(512), 0, stream>>>(AT, Kq, BTv, Vtf, bia, out);
}

// Round 6
// 121.926 us; speedup vs baseline: 1.3666x; 1.3666x over previous
//
#include <hip/hip_runtime.h>

// ---------- helpers ----------
__device__ __forceinline__ unsigned short f2b(float f) {
    unsigned int u = __builtin_bit_cast(unsigned int, f);
    u += 0x7fffu + ((u >> 16) & 1u);   // round-to-nearest-even
    return (unsigned short)(u >> 16);
}
__device__ __forceinline__ float fastrcp(float x) {
    return __builtin_amdgcn_rcpf(x);   // ~1e-7 rel err, invisible under bf16
}
// packed f32x2 -> bf16x2 (RTNE, same rounding as f2b), 1 instruction
__device__ __forceinline__ unsigned int cvt_pk_bf16(float lo, float hi) {
    unsigned int r;
    asm("v_cvt_pk_bf16_f32 %0, %1, %2" : "=v"(r) : "v"(lo), "v"(hi));
    return r;
}
// DPP wave64 sum: after chain, lane 63 holds the full sum; broadcast via readlane.
template<int CTRL>
__device__ __forceinline__ float dpp_add(float x) {
    int s = __builtin_amdgcn_update_dpp(0, __builtin_bit_cast(int, x), CTRL, 0xf, 0xf, true);
    return x + __builtin_bit_cast(float, s);
}
__device__ __forceinline__ float wave_sum_bcast(float x) {
    x = dpp_add<0x111>(x);   // row_shr:1
    x = dpp_add<0x112>(x);   // row_shr:2
    x = dpp_add<0x114>(x);   // row_shr:4
    x = dpp_add<0x118>(x);   // row_shr:8  -> lane 15/31/47/63 = row sums
    x = dpp_add<0x142>(x);   // row_bcast:15
    x = dpp_add<0x143>(x);   // row_bcast:31 -> lane 63 = total
    return __builtin_bit_cast(float,
        __builtin_amdgcn_readlane(__builtin_bit_cast(int, x), 63));
}

typedef short bf16x8_t __attribute__((ext_vector_type(8)));
typedef float f32x4_t  __attribute__((ext_vector_type(4)));

// Problem dims
#define NB   16384   // batch
#define AD   1024    // A dim
#define YD   128     // output dim

// =====================================================================
// Kernel 1: Vt in FRAGMENT-MAJOR layout (unchanged — validated).
//   Logical B row n (0..255), col a (0..1023):  val = Kp[a][n>>7]*U[2a+(n>>7)][n&127]
//   Physical: T=n>>4, rr=n&15, CQ=a>>3, e=a&7
//             Vtf[T*16384 + CQ*128 + rr*8 + e]
// =====================================================================
__global__ __launch_bounds__(256) void vt_kernel(
    const float* __restrict__ Kq,   // [1024][2] f32
    const float* __restrict__ U,    // [2048][128] f32
    unsigned short* __restrict__ Vtf) // [16][128][16][8] bf16
{
    int o  = blockIdx.x * 256 + threadIdx.x;
    int T  = o >> 14;
    int CQ = (o >> 7) & 127;
    int rr = (o >> 3) & 15;
    int e  = o & 7;
    int n  = T * 16 + rr;
    int a  = CQ * 8 + e;
    int j  = n >> 7;
    int y  = n & 127;
    float k  = Kq[2 * a + j];
    float uv = U[(size_t)(2 * a + j) * YD + y];
    Vtf[o] = f2b(k * k * uv);
}

// =====================================================================
// Kernel 2: FUSED row-solve + GEMM + combine.
// 512 threads (8 waves), BM=16 rows/block, 1024 blocks.
// LDS = 32KB A-tile + 128B bf -> LDS allows 4 blocks/CU = 32 waves/CU
// = 8 waves/SIMD.  __launch_bounds__(512,4): 128-VGPR budget — round 4
// measured 52 VGPR under this bound, so 8 waves/SIMD is reached via the
// natural VGPR count WITHOUT spills (round 5's (512,8) clamped to 32
// VGPR and spilled ~190 MB to scratch — the regression).
// Phase 1: wave w owns rows w*2, w*2+1. Moments -> DPP wave-sum ->
//          8-iter closed-form solve -> af bf16 via v_cvt_pk_bf16_f32
//          into swizzled LDS A-tile.  (validated math)
// Phase 2: barrier-free k-loop; wave w owns n-tiles {w, w+8};
//          A frags from LDS, B frags reg-dbuf straight from L2.
// =====================================================================
__global__ __launch_bounds__(512, 4) void fused_kernel(
    const float* __restrict__ AT,            // [16384][1024] f32
    const float* __restrict__ Kq,            // [1024][2] f32
    const float* __restrict__ BTv,           // [2] f32
    const unsigned short* __restrict__ Vtf,  // fragment-major bf16
    const float* __restrict__ bias,          // [128] f32
    float* __restrict__ out)                 // [16384][128] f32
{
    __shared__ __align__(16) unsigned short lA[16 * 1024];    // 32 KB
    __shared__ float lbf[16][2];

    const int t    = threadIdx.x;
    const int lane = t & 63;
    const int w    = t >> 6;          // wave id 0..7
    const int mtile = blockIdx.x;     // 0..1023

    // =================== Phase 1: row solve (2 rows/wave) ===================
    // lane owns columns a = c*256 + lane*4 + e, c=0..3, e=0..3
    float kp0[16], kp1[16];
#pragma unroll
    for (int c = 0; c < 4; ++c) {
        int base = c * 256 + lane * 4;
        float4 k0v = *(const float4*)(Kq + 2 * base);
        float4 k1v = *(const float4*)(Kq + 2 * base + 4);
        kp0[c * 4 + 0] = k0v.x * k0v.x; kp1[c * 4 + 0] = k0v.y * k0v.y;
        kp0[c * 4 + 1] = k0v.z * k0v.z; kp1[c * 4 + 1] = k0v.w * k0v.w;
        kp0[c * 4 + 2] = k1v.x * k1v.x; kp1[c * 4 + 2] = k1v.y * k1v.y;
        kp0[c * 4 + 3] = k1v.z * k1v.z; kp1[c * 4 + 3] = k1v.w * k1v.w;
    }
    const float bt0 = BTv[0], bt1 = BTv[1];

    const float* atb = AT + (size_t)(mtile * 16 + w * 2) * AD;

    float ta[2][16];   // both rows loaded upfront (8 independent dwordx4)
#pragma unroll
    for (int r = 0; r < 2; ++r) {
#pragma unroll
        for (int c = 0; c < 4; ++c) {
            float4 av = *(const float4*)(atb + (size_t)r * AD + c * 256 + lane * 4);
            ta[r][c * 4 + 0] = av.x; ta[r][c * 4 + 1] = av.y;
            ta[r][c * 4 + 2] = av.z; ta[r][c * 4 + 3] = av.w;
        }
    }

#pragma unroll
    for (int r = 0; r < 2; ++r) {
        // moments: 0:M0 1:M1 2:M00 3:M01 4:M11 5:M000 6:M001 7:M011 8:M111
        float M[9];
#pragma unroll
        for (int i2 = 0; i2 < 9; ++i2) M[i2] = 0.f;
#pragma unroll
        for (int e = 0; e < 16; ++e) {
            float tv = ta[r][e], p = kp0[e], q2 = kp1[e];
            float u0 = tv * p, u1 = tv * q2;
            M[0] += u0; M[1] += u1;
            float u00 = u0 * p, u01 = u0 * q2, u11 = u1 * q2;
            M[2] += u00; M[3] += u01; M[4] += u11;
            M[5] += u00 * p; M[6] += u00 * q2; M[7] += u01 * q2; M[8] += u11 * q2;
        }
        // DPP reduce (no DS ops), result uniform via readlane
#pragma unroll
        for (int i2 = 0; i2 < 9; ++i2) M[i2] = wave_sum_bcast(M[i2]);

        float bf0 = 0.f, bf1 = 0.f;
#pragma unroll
        for (int it = 0; it < 8; ++it) {
            float q00 = bf0 * bf0, q01 = bf0 * bf1, q11 = bf1 * bf1;
            float s0 = M[0] - (bf0 * M[2] + bf1 * M[3]) + (q00 * M[5] + 2.f * q01 * M[6] + q11 * M[7]);
            float s1 = M[1] - (bf0 * M[3] + bf1 * M[4]) + (q00 * M[6] + 2.f * q01 * M[7] + q11 * M[8]);
            bf0 = bt0 * fastrcp(1.f + s0);
            bf1 = bt1 * fastrcp(1.f + s1);
        }
        const int m = w * 2 + r;
        if (lane == 0) { lbf[m][0] = bf0; lbf[m][1] = bf1; }

        // af -> bf16 (cvt_pk, RTNE) -> swizzled LDS A-tile (layout unchanged)
#pragma unroll
        for (int c = 0; c < 4; ++c) {
            float v[4];
#pragma unroll
            for (int e = 0; e < 4; ++e) {
                int idx = c * 4 + e;
                v[e] = ta[r][idx] * fastrcp(1.f + bf0 * kp0[idx] + bf1 * kp1[idx]);
            }
            uint2 pk;
            pk.x = cvt_pk_bf16(v[0], v[1]);
            pk.y = cvt_pk_bf16(v[2], v[3]);
            int cg = c * 4 + (lane >> 4);
            int cl = (lane >> 1) & 7;
            int off = (m * 128 + cg * 8 + (cl ^ (m & 7))) * 8 + (lane & 1) * 4;
            *(uint2*)(&lA[off]) = pk;
        }
    }

    __syncthreads();   // the ONLY barrier: lA/lbf now visible to all waves

    // =================== Phase 2: barrier-free GEMM ===================
    const int rr = lane & 15;      // row/col within 16-tile
    const int hb = lane >> 4;      // quarter-wave
    const int rx = rr & 7;         // A-swizzle key (m-row = rr, (rr&7))

    // wave w owns n-tiles {w, w+8}: y = w*16+rr and y+128
    const unsigned short* pB = Vtf + (size_t)w * 16384 + hb * 128 + rr * 8;

    f32x4_t acc[2];
#pragma unroll
    for (int j = 0; j < 2; ++j) acc[j] = (f32x4_t){0.f, 0.f, 0.f, 0.f};

    bf16x8_t fbA[2], fbB[2];

    auto loadB = [&](bf16x8_t* fb, int k0, int kk) {
        int ke = k0 * 16 + kk * 512;              // uniform elem offset
        fb[0] = *(const bf16x8_t*)(pB + ke);            // tile w
        fb[1] = *(const bf16x8_t*)(pB + ke + 131072);   // tile w+8
    };
    auto compute = [&](const bf16x8_t* fb, int k0, int kk) {
        const int cq = kk * 4 + hb;
        bf16x8_t fa = *(const bf16x8_t*)(
            &lA[((rr * 128) + (k0 >> 6) * 8 + (cq ^ rx)) * 8]);
#pragma unroll
        for (int j = 0; j < 2; ++j)
            acc[j] = __builtin_amdgcn_mfma_f32_16x16x32_bf16(fa, fb[j], acc[j], 0, 0, 0);
    };

    loadB(fbA, 0, 0);
    loadB(fbB, 0, 1);
#pragma unroll 1
    for (int k0 = 0; k0 < AD; k0 += 64) {
        __builtin_amdgcn_s_setprio(1);
        compute(fbA, k0, 0);
        __builtin_amdgcn_s_setprio(0);
        if (k0 + 64 < AD) loadB(fbA, k0 + 64, 0);
        __builtin_amdgcn_s_setprio(1);
        compute(fbB, k0, 1);
        __builtin_amdgcn_s_setprio(0);
        if (k0 + 64 < AD) loadB(fbB, k0 + 64, 1);
    }

    // =================== Epilogue ===================
    // C/D layout: col = lane&15 (n within tile), row = (lane>>4)*4 + reg.
    // acc[0] (tile w, y-cols) pairs with acc[1] (tile w+8, y+128 cols).
    const int mloc  = hb * 4;
    const int mbase = mtile * 16 + mloc;
    float2 bfv[4];
#pragma unroll
    for (int r = 0; r < 4; ++r)
        bfv[r] = *(const float2*)(&lbf[mloc + r][0]);
    const int y = w * 16 + rr;
    const float bv = bias[y];
#pragma unroll
    for (int r = 0; r < 4; ++r) {
        float val = bfv[r].x * acc[0][r] + bfv[r].y * acc[1][r] + bv;
        out[(size_t)(mbase + r) * YD + y] = val;
    }
}

// =====================================================================
extern "C" void kernel_launch(void* const* d_in, const int* in_sizes, int n_in,
                              void* d_out, int out_size, void* d_ws, size_t ws_size,
                              hipStream_t stream) {
    const float* AT  = (const float*)d_in[0];  // [16384][1024] f32
    const float* Kq  = (const float*)d_in[1];  // [1024][2] f32
    const float* BTv = (const float*)d_in[2];  // [2] f32
    const float* U   = (const float*)d_in[3];  // [2048][128] f32
    const float* bia = (const float*)d_in[4];  // [128] f32
    float* out = (float*)d_out;

    unsigned short* Vtf = (unsigned short*)d_ws;  // 512 KB bf16 fragment-major

    vt_kernel<<<dim3(1024), dim3(256), 0, stream>>>(Kq, U, Vtf);
    fused_kernel<<<dim3(NB / 16), dim3(512), 0, stream>>>(AT, Kq, BTv, Vtf, bia, out);
}